// Round 1
// baseline (828.220 us; speedup 1.0000x reference)
//
#include <hip/hip_runtime.h>

typedef unsigned short u16;
typedef short sx8 __attribute__((ext_vector_type(8)));
typedef float fx4 __attribute__((ext_vector_type(4)));
typedef unsigned short ux8 __attribute__((ext_vector_type(8)));

#define N_B   4
#define LQ_C  13294
#define D_C   256
#define NH_C  8
#define NL_C  4
#define NP_C  4
#define CH_C  32
#define LIN_C 13294
#define MROWS (N_B * LQ_C)   // 53176

static __device__ __forceinline__ u16 f2bf(float f) {
    unsigned u = __builtin_bit_cast(unsigned, f);
    u += 0x7fffu + ((u >> 16) & 1u);
    return (u16)(u >> 16);
}
static __device__ __forceinline__ float bf2f(u16 h) {
    unsigned u = ((unsigned)h) << 16;
    return __builtin_bit_cast(float, u);
}

// ---------------------------------------------------------------------------
// Prep: transpose + convert weights to bf16 [col][k] layout; concat biases.
// ---------------------------------------------------------------------------
__global__ __launch_bounds__(256) void prep_kernel(
    const float* __restrict__ W_off, const float* __restrict__ b_off,
    const float* __restrict__ W_attn, const float* __restrict__ b_attn,
    const float* __restrict__ W_val, const float* __restrict__ W_out,
    u16* __restrict__ WTcat, u16* __restrict__ WTval, u16* __restrict__ WTout,
    float* __restrict__ biascat)
{
    int e = blockIdx.x * 256 + threadIdx.x;
    if (e < 384 * 256) {
        int col = e >> 8, k = e & 255;
        float v = (col < 256) ? W_off[k * 256 + col] : W_attn[k * 128 + (col - 256)];
        WTcat[e] = f2bf(v);
    } else if (e < 384 * 256 + 65536) {
        int e2 = e - 384 * 256;
        int col = e2 >> 8, k = e2 & 255;
        WTval[e2] = f2bf(W_val[k * 256 + col]);
    } else if (e < 384 * 256 + 131072) {
        int e2 = e - 384 * 256 - 65536;
        int col = e2 >> 8, k = e2 & 255;
        WTout[e2] = f2bf(W_out[k * 256 + col]);
    }
    if (e < 384) biascat[e] = (e < 256) ? b_off[e] : b_attn[e - 256];
}

// ---------------------------------------------------------------------------
// GEMM: C[M,NC] = A[M,256] @ W[256,NC] + bias.  W passed pre-transposed bf16
// WT[NC][256].  128x128 tile, BK=32, 4 waves, 16x16x32 bf16 MFMA.
// LDS tiles padded to stride 40 u16 (80B) -> (5r+c)%8 spreads bank quads.
// ---------------------------------------------------------------------------
template <int ABF, int CBF>
__global__ __launch_bounds__(256) void gemm_k256(
    const void* __restrict__ Av, const u16* __restrict__ WT,
    const float* __restrict__ bias, void* __restrict__ Cv, int M, int NC)
{
    __shared__ u16 As[128 * 40];
    __shared__ u16 Bs[128 * 40];

    const int tid  = threadIdx.x;
    const int row0 = blockIdx.x * 128;
    const int col0 = blockIdx.y * 128;
    const int lane = tid & 63;
    const int wv   = tid >> 6;
    const int wr   = (wv >> 1) * 64;
    const int wc   = (wv & 1) * 64;
    const int lr   = lane & 15;
    const int lk   = lane >> 4;

    fx4 acc[4][4];
#pragma unroll
    for (int i = 0; i < 4; i++)
#pragma unroll
        for (int j = 0; j < 4; j++) acc[i][j] = (fx4){0.f, 0.f, 0.f, 0.f};

    const int sr = tid >> 1;  // staging row 0..127
    const int sh = tid & 1;   // k-half 0/1 (16 elems each)
    const bool aok = (row0 + sr) < M;

    for (int kk = 0; kk < 256; kk += 32) {
        ux8 p0 = (ux8)0, p1 = (ux8)0;
        if (ABF == 0) {
            if (aok) {
                const fx4* s4 = (const fx4*)((const float*)Av +
                                 (size_t)(row0 + sr) * 256 + kk + sh * 16);
                fx4 v0 = s4[0], v1 = s4[1], v2 = s4[2], v3 = s4[3];
#pragma unroll
                for (int e = 0; e < 4; e++) {
                    p0[e]     = f2bf(v0[e]);
                    p0[4 + e] = f2bf(v1[e]);
                    p1[e]     = f2bf(v2[e]);
                    p1[4 + e] = f2bf(v3[e]);
                }
            }
        } else {
            if (aok) {
                const ux8* s8 = (const ux8*)((const u16*)Av +
                                 (size_t)(row0 + sr) * 256 + kk + sh * 16);
                p0 = s8[0];
                p1 = s8[1];
            }
        }
        const int abase = sr * 40 + sh * 16;
        *(ux8*)&As[abase]     = p0;
        *(ux8*)&As[abase + 8] = p1;

        const ux8* wsp = (const ux8*)(WT + (size_t)(col0 + sr) * 256 + kk + sh * 16);
        *(ux8*)&Bs[abase]     = wsp[0];
        *(ux8*)&Bs[abase + 8] = wsp[1];

        __syncthreads();

        sx8 af[4], bfr[4];
#pragma unroll
        for (int i = 0; i < 4; i++) {
            int ar = wr + i * 16 + lr;
            af[i] = __builtin_bit_cast(sx8, *(const ux8*)&As[ar * 40 + lk * 8]);
            int bc = wc + i * 16 + lr;
            bfr[i] = __builtin_bit_cast(sx8, *(const ux8*)&Bs[bc * 40 + lk * 8]);
        }
#pragma unroll
        for (int i = 0; i < 4; i++)
#pragma unroll
            for (int j = 0; j < 4; j++)
                acc[i][j] = __builtin_amdgcn_mfma_f32_16x16x32_bf16(
                    af[i], bfr[j], acc[i][j], 0, 0, 0);

        __syncthreads();
    }

#pragma unroll
    for (int j = 0; j < 4; j++) {
        int colg = col0 + wc + j * 16 + lr;
        float bv = bias[colg];
#pragma unroll
        for (int i = 0; i < 4; i++) {
#pragma unroll
            for (int rg = 0; rg < 4; rg++) {
                int rowg = row0 + wr + i * 16 + lk * 4 + rg;
                if (rowg < M) {
                    float v = acc[i][j][rg] + bv;
                    if (CBF)
                        ((u16*)Cv)[(size_t)rowg * NC + colg] = f2bf(v);
                    else
                        ((float*)Cv)[(size_t)rowg * NC + colg] = v;
                }
            }
        }
    }
}

// ---------------------------------------------------------------------------
// Sampling: one block per (n,q); 8 heads x 32 channels.
// offattn row [384] bf16: cols 0..255 offsets (h*16+l*4+p)*2+{x,y}, 256..383
// logits h*16+l*4+p.  value bf16 [N*LIN][256] col = head*32+ch.
// ---------------------------------------------------------------------------
__global__ __launch_bounds__(256) void sample_kernel(
    const float* __restrict__ ref, const u16* __restrict__ offattn,
    const u16* __restrict__ value, u16* __restrict__ out_pre)
{
    const int q = blockIdx.x;       // n*LQ + q
    const int n = q / LQ_C;
    const int h = threadIdx.x >> 5;
    const int c = threadIdx.x & 31;

    const u16* oa = offattn + (size_t)q * 384;

    float lg[16];
    float mx = -1e30f;
#pragma unroll
    for (int t = 0; t < 16; t++) {
        lg[t] = bf2f(oa[256 + h * 16 + t]);
        mx = fmaxf(mx, lg[t]);
    }
    float s = 0.f;
#pragma unroll
    for (int t = 0; t < 16; t++) {
        lg[t] = __expf(lg[t] - mx);
        s += lg[t];
    }
    const float inv = 1.f / s;

    const int Hs_[4] = {100, 50, 25, 13};
    const int Ws_[4] = {100, 50, 25, 13};
    const int st_[4] = {0, 10000, 12500, 13125};

    const float* rp = ref + (size_t)q * 8;
    float acc = 0.f;

#pragma unroll
    for (int l = 0; l < 4; l++) {
        const int Hh = Hs_[l], Ww = Ws_[l];
        const u16* vb = value + ((size_t)(n * LIN_C + st_[l])) * 256 + h * 32 + c;
        const float rx = rp[l * 2 + 0], ry = rp[l * 2 + 1];
#pragma unroll
        for (int p = 0; p < 4; p++) {
            const int oi = (h * 16 + l * 4 + p) * 2;
            const float x = rx * Ww + bf2f(oa[oi])     - 0.5f;
            const float y = ry * Hh + bf2f(oa[oi + 1]) - 0.5f;
            const float fxx = floorf(x), fyy = floorf(y);
            const float wx = x - fxx, wy = y - fyy;
            const int x0 = (int)fxx, y0 = (int)fyy;
            const float a = lg[l * 4 + p] * inv;
            const float w00 = (1.f - wx) * (1.f - wy) * a;
            const float w10 = wx * (1.f - wy) * a;
            const float w01 = (1.f - wx) * wy * a;
            const float w11 = wx * wy * a;
            const bool xv0 = (x0 >= 0) && (x0 < Ww);
            const bool xv1 = (x0 + 1 >= 0) && (x0 + 1 < Ww);
            if (y0 >= 0 && y0 < Hh) {
                const u16* row = vb + (size_t)y0 * Ww * 256;
                if (xv0) acc += w00 * bf2f(row[(size_t)x0 * 256]);
                if (xv1) acc += w10 * bf2f(row[(size_t)(x0 + 1) * 256]);
            }
            if (y0 + 1 >= 0 && y0 + 1 < Hh) {
                const u16* row = vb + (size_t)(y0 + 1) * Ww * 256;
                if (xv0) acc += w01 * bf2f(row[(size_t)x0 * 256]);
                if (xv1) acc += w11 * bf2f(row[(size_t)(x0 + 1) * 256]);
            }
        }
    }
    out_pre[(size_t)q * 256 + h * 32 + c] = f2bf(acc);
}

// ---------------------------------------------------------------------------
extern "C" void kernel_launch(void* const* d_in, const int* in_sizes, int n_in,
                              void* d_out, int out_size, void* d_ws, size_t ws_size,
                              hipStream_t stream)
{
    const float* query   = (const float*)d_in[0];
    const float* refp    = (const float*)d_in[1];
    const float* inflat  = (const float*)d_in[2];
    const float* W_off   = (const float*)d_in[5];
    const float* b_off   = (const float*)d_in[6];
    const float* W_attn  = (const float*)d_in[7];
    const float* b_attn  = (const float*)d_in[8];
    const float* W_val   = (const float*)d_in[9];
    const float* b_val   = (const float*)d_in[10];
    const float* W_out   = (const float*)d_in[11];
    const float* b_out   = (const float*)d_in[12];

    char* ws = (char*)d_ws;
    u16* WTcat = (u16*)ws;   ws += (size_t)384 * 256 * 2;
    u16* WTval = (u16*)ws;   ws += (size_t)256 * 256 * 2;
    u16* WTout = (u16*)ws;   ws += (size_t)256 * 256 * 2;
    float* biascat = (float*)ws; ws += 512 * 4;
    u16* value   = (u16*)ws; ws += (size_t)MROWS * 256 * 2;
    u16* offattn = (u16*)ws; ws += (size_t)MROWS * 384 * 2;
    u16* out_pre = (u16*)ws; ws += (size_t)MROWS * 256 * 2;

    prep_kernel<<<896, 256, 0, stream>>>(W_off, b_off, W_attn, b_attn, W_val,
                                         W_out, WTcat, WTval, WTout, biascat);

    dim3 g2((MROWS + 127) / 128, 2);
    dim3 g3((MROWS + 127) / 128, 3);

    gemm_k256<0, 1><<<g2, 256, 0, stream>>>(inflat, WTval, b_val, value, MROWS, 256);
    gemm_k256<0, 1><<<g3, 256, 0, stream>>>(query, WTcat, biascat, offattn, MROWS, 384);
    sample_kernel<<<MROWS, 256, 0, stream>>>(refp, offattn, value, out_pre);
    gemm_k256<1, 0><<<g2, 256, 0, stream>>>(out_pre, WTout, b_out, d_out, MROWS, 256);
}